// Round 1
// baseline (257.019 us; speedup 1.0000x reference)
//
#include <hip/hip_runtime.h>
#include <cstdint>

#pragma clang fp contract(off)

#define NB      32
#define NC      18
#define NA      8400
#define NCH     (4 + NC)
#define TOPK    300
#define NBINS   4096
#define CAND_CAP 1024
#define CONF    0.25f
#define IOU_T   0.45f
#define BASEBITS 0x3E800000u   // bits of 0.25f

__device__ __forceinline__ float sigmoidf(float x) {
    return 1.0f / (1.0f + expf(-x));
}

// Suffix-find over a 4096-bin histogram with 256 threads:
// finds bin T such that (#elems in bins > T) < target <= (#elems in bins >= T).
// Writes *s_bin (crossing bin, stays -1 if total < target), *s_above (count strictly above),
// *s_total (total count). Caller must init *s_bin = -1 (single thread) before calling.
__device__ inline void suffix_find(unsigned int* hist, unsigned int* chunk, int target,
                                   int tid, int* s_bin, int* s_above, int* s_total) {
    unsigned int sum = 0;
    const int base = tid * 16;
#pragma unroll
    for (int k = 0; k < 16; ++k) sum += hist[base + k];
    chunk[tid] = sum;
    __syncthreads();
    if (tid == 0) {
        unsigned int acc = 0;
        for (int t = 255; t >= 0; --t) { unsigned int s = chunk[t]; chunk[t] = acc; acc += s; }
        *s_total = (int)acc;
    }
    __syncthreads();
    unsigned int acc = chunk[tid];
    for (int bin = base + 15; bin >= base; --bin) {
        unsigned int cnt = hist[bin];
        if (acc < (unsigned int)target && acc + cnt >= (unsigned int)target) {
            *s_bin = bin;
            *s_above = (int)acc;
        }
        acc += cnt;
    }
    __syncthreads();
}

__global__ __launch_bounds__(256) void yolo_post(const float* __restrict__ in,
                                                 float* __restrict__ out) {
    __shared__ unsigned int hist[NBINS];        // 16 KB (reused level1/level2)
    __shared__ unsigned int chunk[256];         // 1 KB
    __shared__ unsigned long long cand[CAND_CAP]; // 8 KB
    __shared__ unsigned long long skey[TOPK];   // 2.4 KB
    __shared__ float bx1[TOPK], by1[TOPK], bx2[TOPK], by2[TOPK], bvv[TOPK]; // 6 KB
    __shared__ unsigned long long supmask[TOPK][5]; // 12 KB
    __shared__ unsigned long long keepw[5];
    __shared__ unsigned int s_cnt;
    __shared__ int s_T1, s_G1, s_T2, s_G2, s_total;

    const int tid = threadIdx.x;
    const int b = blockIdx.x / NC;
    const int c = blockIdx.x % NC;
    const float* cls = in + (size_t)b * NCH * NA + (size_t)(4 + c) * NA;
    const float* box = in + (size_t)b * NCH * NA;

    // ---- P0: init ----
    for (int i = tid; i < NBINS; i += 256) hist[i] = 0;
    if (tid == 0) { s_cnt = 0; s_T1 = -1; s_T2 = -1; s_G1 = 0; s_G2 = 0; }
    __syncthreads();

    // ---- P1: level-1 histogram on top 12 bits of (score_bits - BASEBITS) ----
    for (int i = tid; i < NA; i += 256) {
        float s = sigmoidf(cls[i]);
        if (s > CONF) {
            unsigned int d = __float_as_uint(s) - BASEBITS;
            if (d > 0xFFFFFFu) d = 0xFFFFFFu;
            atomicAdd(&hist[d >> 12], 1u);
        }
    }
    __syncthreads();

    // ---- P2: find level-1 crossing bin ----
    suffix_find(hist, chunk, TOPK, tid, &s_T1, &s_G1, &s_total);

    const bool selAll = (s_T1 < 0);   // fewer than TOPK positives: take them all
    const int T1 = s_T1;
    const int G1 = s_G1;
    unsigned int diff_thr = 0;

    if (!selAll) {
        // ---- P3: level-2 histogram on low 12 bits, within bin T1 ----
        __syncthreads();
        for (int i = tid; i < NBINS; i += 256) hist[i] = 0;
        __syncthreads();
        for (int i = tid; i < NA; i += 256) {
            float s = sigmoidf(cls[i]);
            if (s > CONF) {
                unsigned int d = __float_as_uint(s) - BASEBITS;
                if (d > 0xFFFFFFu) d = 0xFFFFFFu;
                if ((int)(d >> 12) == T1) atomicAdd(&hist[d & 0xFFFu], 1u);
            }
        }
        __syncthreads();
        suffix_find(hist, chunk, TOPK - G1, tid, &s_T2, &s_G2, &s_total);
        diff_thr = ((unsigned int)T1 << 12) | (unsigned int)s_T2;
    }
    __syncthreads();

    // ---- P4: collect candidates (score strictly above cutoff, plus exact-cutoff ties) ----
    for (int i = tid; i < NA; i += 256) {
        float s = sigmoidf(cls[i]);
        if (s > CONF) {
            unsigned int d = __float_as_uint(s) - BASEBITS;
            if (d > 0xFFFFFFu) d = 0xFFFFFFu;
            if (selAll || d >= diff_thr) {
                unsigned int p = atomicAdd(&s_cnt, 1u);
                if (p < CAND_CAP)
                    cand[p] = ((unsigned long long)d << 32) |
                              (unsigned long long)(~(unsigned int)i);
            }
        }
    }
    __syncthreads();
    const int M = min((int)s_cnt, CAND_CAP);
    const int numSel = min(M, TOPK);

    // ---- P5: rank-by-counting sort (keys unique: index embedded) ----
    for (int e = tid; e < M; e += 256) {
        unsigned long long k = cand[e];
        int rank = 0;
        for (int o = 0; o < M; ++o) rank += (cand[o] > k) ? 1 : 0;
        if (rank < TOPK) skey[rank] = k;
    }
    __syncthreads();

    // ---- P6: gather boxes, convert cxcywh -> xyxy ----
    for (int r = tid; r < numSel; r += 256) {
        unsigned long long k = skey[r];
        unsigned int i = ~(unsigned int)(k & 0xFFFFFFFFull);
        unsigned int d = (unsigned int)(k >> 32);
        float val = __uint_as_float(d + BASEBITS);
        float cx = box[i];
        float cy = box[NA + i];
        float w  = box[2 * NA + i];
        float h  = box[3 * NA + i];
        float hw = w * 0.5f, hh = h * 0.5f;
        bx1[r] = cx - hw; by1[r] = cy - hh;
        bx2[r] = cx + hw; by2[r] = cy + hh;
        bvv[r] = val;
    }
    __syncthreads();

    // ---- P7: suppression bitmask matrix, wave-parallel via ballot ----
    {
        const int wave = tid >> 6;
        const int lane = tid & 63;
        const int ntasks = numSel * 5;
        for (int t = wave; t < ntasks; t += 4) {
            const int i = t / 5;
            const int w = t - i * 5;
            const int j = w * 64 + lane;
            bool sup = false;
            if (j < numSel && j > i) {
                float xx1 = fmaxf(bx1[i], bx1[j]);
                float yy1 = fmaxf(by1[i], by1[j]);
                float xx2 = fminf(bx2[i], bx2[j]);
                float yy2 = fminf(by2[i], by2[j]);
                float iw = fmaxf(xx2 - xx1, 0.0f);
                float ih = fmaxf(yy2 - yy1, 0.0f);
                float inter = iw * ih;
                float ai = fmaxf(bx2[i] - bx1[i], 0.0f) * fmaxf(by2[i] - by1[i], 0.0f);
                float aj = fmaxf(bx2[j] - bx1[j], 0.0f) * fmaxf(by2[j] - by1[j], 0.0f);
                float un = ai + aj - inter;
                float iou = inter / fmaxf(un, 1e-9f);
                sup = iou > IOU_T;
            }
            unsigned long long bal = __ballot(sup);
            if (lane == 0) supmask[i][w] = bal;
        }
    }
    __syncthreads();

    // ---- P8: serial greedy suppression scan (single thread, 300 x 5 ORs) ----
    if (tid == 0) {
        unsigned long long rem0 = 0, rem1 = 0, rem2 = 0, rem3 = 0, rem4 = 0;
        for (int i = 0; i < numSel; ++i) {
            unsigned long long r;
            switch (i >> 6) {
                case 0: r = rem0; break;
                case 1: r = rem1; break;
                case 2: r = rem2; break;
                case 3: r = rem3; break;
                default: r = rem4; break;
            }
            if (!((r >> (i & 63)) & 1ull)) {
                rem0 |= supmask[i][0];
                rem1 |= supmask[i][1];
                rem2 |= supmask[i][2];
                rem3 |= supmask[i][3];
                rem4 |= supmask[i][4];
            }
        }
        keepw[0] = ~rem0; keepw[1] = ~rem1; keepw[2] = ~rem2;
        keepw[3] = ~rem3; keepw[4] = ~rem4;
    }
    __syncthreads();

    // ---- P9: write output rows (zeros when suppressed / invalid) ----
    float* outp = out + (size_t)b * (NC * TOPK * 6) + (size_t)c * (TOPK * 6);
    for (int el = tid; el < TOPK * 6; el += 256) {
        const int r = el / 6;
        const int f = el - r * 6;
        float v = 0.0f;
        if (r < numSel && ((keepw[r >> 6] >> (r & 63)) & 1ull)) {
            switch (f) {
                case 0: v = bx1[r]; break;
                case 1: v = by1[r]; break;
                case 2: v = bx2[r]; break;
                case 3: v = by2[r]; break;
                case 4: v = bvv[r]; break;
                default: v = (float)c; break;
            }
        }
        outp[el] = v;
    }
}

extern "C" void kernel_launch(void* const* d_in, const int* in_sizes, int n_in,
                              void* d_out, int out_size, void* d_ws, size_t ws_size,
                              hipStream_t stream) {
    const float* in = (const float*)d_in[0];
    float* out = (float*)d_out;
    yolo_post<<<NB * NC, 256, 0, stream>>>(in, out);
}

// Round 2
// 208.690 us; speedup vs baseline: 1.2316x; 1.2316x over previous
//
#include <hip/hip_runtime.h>
#include <cstdint>

#pragma clang fp contract(off)

#define NB      32
#define NC      18
#define NA      8400
#define NCH     (4 + NC)
#define TOPK    300
#define NBINS   4096
#define CAND_CAP 1024
#define CONF    0.25f
#define IOU_T   0.45f
#define BASEBITS 0x3E800000u   // bits of 0.25f

__device__ __forceinline__ float sigmoidf(float x) {
    return 1.0f / (1.0f + expf(-x));
}

__device__ __forceinline__ unsigned int score_key(float x) {
    // 24-bit monotonic key for sigmoid(x) in (0.25, 1]; 0 means "below conf"
    float s = sigmoidf(x);
    if (!(s > CONF)) return 0u;
    unsigned int d = __float_as_uint(s) - BASEBITS;
    if (d > 0xFFFFFFu) d = 0xFFFFFFu;
    return d;
}

struct PhaseB {
    unsigned long long skey[TOPK];                       // 2400 B
    float bx1[TOPK], by1[TOPK], bx2[TOPK], by2[TOPK], bvv[TOPK]; // 6000 B
    unsigned long long supmask[TOPK][5];                 // 12000 B
};

union U1 {
    unsigned int keys[NA];     // 33600 B  (live P1..P4)
    PhaseB pb;                 // 20400 B  (live P5..P9)
};

union U2 {
    struct {
        unsigned int hist[NBINS];  // 16384 B (live P1..P2)
        unsigned int wtot[4];
    } ph;
    unsigned long long cand[CAND_CAP]; // 8192 B (live P4..P5)
};

__global__ __launch_bounds__(256) void yolo_post(const float* __restrict__ in,
                                                 float* __restrict__ out) {
    __shared__ U1 u1;
    __shared__ U2 u2;
    __shared__ unsigned long long keepw[5];
    __shared__ unsigned int s_cnt;
    __shared__ int s_T1;

    const int tid = threadIdx.x;
    const int b = blockIdx.x / NC;
    const int c = blockIdx.x % NC;
    const float* cls = in + (size_t)b * NCH * NA + (size_t)(4 + c) * NA;
    const float* box = in + (size_t)b * NCH * NA;

    // ---- P0: init ----
    for (int i = tid; i < NBINS; i += 256) u2.ph.hist[i] = 0;
    if (tid == 0) { s_cnt = 0; s_T1 = -1; }
    __syncthreads();

    // ---- P1: single global pass: keys -> LDS, level-1 histogram ----
    {
        const float4* cls4 = (const float4*)cls;
        uint4* keys4 = (uint4*)u1.keys;
        for (int q = tid; q < NA / 4; q += 256) {
            float4 x = cls4[q];
            uint4 k;
            k.x = score_key(x.x);
            k.y = score_key(x.y);
            k.z = score_key(x.z);
            k.w = score_key(x.w);
            keys4[q] = k;
            if (k.x) atomicAdd(&u2.ph.hist[k.x >> 12], 1u);
            if (k.y) atomicAdd(&u2.ph.hist[k.y >> 12], 1u);
            if (k.z) atomicAdd(&u2.ph.hist[k.z >> 12], 1u);
            if (k.w) atomicAdd(&u2.ph.hist[k.w >> 12], 1u);
        }
    }
    __syncthreads();

    // ---- P2: find crossing bin T1 (count above bins > T1 is < TOPK <= count >= T1) ----
    {
        const int base = tid * 16;
        unsigned int v = 0;
#pragma unroll
        for (int k = 0; k < 16; ++k) v += u2.ph.hist[base + k];
        // wave reverse-inclusive scan (suffix within wave)
        const int lane = tid & 63;
        unsigned int s = v;
#pragma unroll
        for (int d = 1; d < 64; d <<= 1) {
            unsigned int o = __shfl_down(s, d, 64);
            if (lane + d < 64) s += o;
        }
        if (lane == 0) u2.ph.wtot[tid >> 6] = s;
        __syncthreads();
        unsigned int above_waves = 0;
        for (int wv = (tid >> 6) + 1; wv < 4; ++wv) above_waves += u2.ph.wtot[wv];
        unsigned int above = s + above_waves - v;  // count in threads strictly after tid
        unsigned int acc = above;
        for (int bin = base + 15; bin >= base; --bin) {
            unsigned int cnt = u2.ph.hist[bin];
            if (acc < (unsigned int)TOPK && acc + cnt >= (unsigned int)TOPK) s_T1 = bin;
            acc += cnt;
        }
    }
    __syncthreads();

    // ---- P4: collect candidates with bin >= T1 (includes crossing-bin ties) ----
    {
        const unsigned int thr = (s_T1 < 0) ? 1u : ((unsigned int)s_T1 << 12);
        const uint4* keys4 = (const uint4*)u1.keys;
        for (int q = tid; q < NA / 4; q += 256) {
            uint4 k = keys4[q];
            const unsigned int i0 = (unsigned int)q * 4u;
#pragma unroll
            for (int t = 0; t < 4; ++t) {
                unsigned int d = (t == 0) ? k.x : (t == 1) ? k.y : (t == 2) ? k.z : k.w;
                if (d && d >= thr) {
                    unsigned int p = atomicAdd(&s_cnt, 1u);
                    if (p < CAND_CAP)
                        u2.cand[p] = ((unsigned long long)d << 32) |
                                     (unsigned long long)(~(i0 + t));
                }
            }
        }
    }
    __syncthreads();
    const int M = min((int)s_cnt, CAND_CAP);
    const int numSel = min(M, TOPK);

    // ---- P5: rank-by-counting sort (keys unique: ~index embedded; desc score, asc idx) ----
    for (int e = tid; e < M; e += 256) {
        unsigned long long k = u2.cand[e];
        int rank = 0;
        for (int o = 0; o < M; ++o) rank += (u2.cand[o] > k) ? 1 : 0;
        if (rank < TOPK) u1.pb.skey[rank] = k;   // aliases keys[] — dead after P4
    }
    __syncthreads();

    // ---- P6: gather boxes (cxcywh -> xyxy) + zero supmask ----
    for (int r = tid; r < numSel; r += 256) {
        unsigned long long k = u1.pb.skey[r];
        unsigned int i = ~(unsigned int)(k & 0xFFFFFFFFull);
        unsigned int d = (unsigned int)(k >> 32);
        float val = __uint_as_float(d + BASEBITS);
        float cx = box[i];
        float cy = box[NA + i];
        float w  = box[2 * NA + i];
        float h  = box[3 * NA + i];
        float hw = w * 0.5f, hh = h * 0.5f;
        u1.pb.bx1[r] = cx - hw; u1.pb.by1[r] = cy - hh;
        u1.pb.bx2[r] = cx + hw; u1.pb.by2[r] = cy + hh;
        u1.pb.bvv[r] = val;
    }
    for (int t = tid; t < TOPK * 5; t += 256)
        ((unsigned long long*)u1.pb.supmask)[t] = 0ull;
    __syncthreads();

    // ---- P7: suppression bitmask matrix, wave-parallel, diagonal-skipped ----
    {
        const int wave = tid >> 6;
        const int lane = tid & 63;
        for (int i = wave; i < numSel; i += 4) {
            const float x1i = u1.pb.bx1[i], y1i = u1.pb.by1[i];
            const float x2i = u1.pb.bx2[i], y2i = u1.pb.by2[i];
            const float ai = fmaxf(x2i - x1i, 0.0f) * fmaxf(y2i - y1i, 0.0f);
            for (int w = i >> 6; w < 5; ++w) {
                const int j = (w << 6) + lane;
                bool sup = false;
                if (j < numSel && j > i) {
                    float xx1 = fmaxf(x1i, u1.pb.bx1[j]);
                    float yy1 = fmaxf(y1i, u1.pb.by1[j]);
                    float xx2 = fminf(x2i, u1.pb.bx2[j]);
                    float yy2 = fminf(y2i, u1.pb.by2[j]);
                    float iw = fmaxf(xx2 - xx1, 0.0f);
                    float ih = fmaxf(yy2 - yy1, 0.0f);
                    float inter = iw * ih;
                    float aj = fmaxf(u1.pb.bx2[j] - u1.pb.bx1[j], 0.0f) *
                               fmaxf(u1.pb.by2[j] - u1.pb.by1[j], 0.0f);
                    float un = ai + aj - inter;
                    float iou = inter / fmaxf(un, 1e-9f);
                    sup = iou > IOU_T;
                }
                unsigned long long bal = __ballot(sup);
                if (lane == 0) u1.pb.supmask[i][w] = bal;
            }
        }
    }
    __syncthreads();

    // ---- P8: serial greedy suppression scan (single thread) ----
    if (tid == 0) {
        unsigned long long rem0 = 0, rem1 = 0, rem2 = 0, rem3 = 0, rem4 = 0;
        for (int i = 0; i < numSel; ++i) {
            unsigned long long r;
            switch (i >> 6) {
                case 0: r = rem0; break;
                case 1: r = rem1; break;
                case 2: r = rem2; break;
                case 3: r = rem3; break;
                default: r = rem4; break;
            }
            if (!((r >> (i & 63)) & 1ull)) {
                rem0 |= u1.pb.supmask[i][0];
                rem1 |= u1.pb.supmask[i][1];
                rem2 |= u1.pb.supmask[i][2];
                rem3 |= u1.pb.supmask[i][3];
                rem4 |= u1.pb.supmask[i][4];
            }
        }
        keepw[0] = ~rem0; keepw[1] = ~rem1; keepw[2] = ~rem2;
        keepw[3] = ~rem3; keepw[4] = ~rem4;
    }
    __syncthreads();

    // ---- P9: write output rows ----
    float* outp = out + (size_t)blockIdx.x * (TOPK * 6);
    for (int el = tid; el < TOPK * 6; el += 256) {
        const int r = el / 6;
        const int f = el - r * 6;
        float v = 0.0f;
        if (r < numSel && ((keepw[r >> 6] >> (r & 63)) & 1ull)) {
            switch (f) {
                case 0: v = u1.pb.bx1[r]; break;
                case 1: v = u1.pb.by1[r]; break;
                case 2: v = u1.pb.bx2[r]; break;
                case 3: v = u1.pb.by2[r]; break;
                case 4: v = u1.pb.bvv[r]; break;
                default: v = (float)c; break;
            }
        }
        outp[el] = v;
    }
}

extern "C" void kernel_launch(void* const* d_in, const int* in_sizes, int n_in,
                              void* d_out, int out_size, void* d_ws, size_t ws_size,
                              hipStream_t stream) {
    const float* in = (const float*)d_in[0];
    float* out = (float*)d_out;
    yolo_post<<<NB * NC, 256, 0, stream>>>(in, out);
}

// Round 3
// 190.092 us; speedup vs baseline: 1.3521x; 1.0978x over previous
//
#include <hip/hip_runtime.h>
#include <cstdint>

#pragma clang fp contract(off)

#define NB      32
#define NC      18
#define NA      8400
#define NCH     (4 + NC)
#define TOPK    300
#define TARGET  316        // TOPK + margin: absorbs sigmoid-tie rank ambiguity
#define NBINS   4096
#define CAND_CAP 1024
#define CONF    0.25f
#define IOU_T   0.45f
#define NT      512
#define NW      (NT / 64)
// sigmoid(x) > 0.25  <=>  x > -ln(3) = -1.0986123.
// Outside [XLO, XHI] the analytic test is provably exact (fp32 sigmoid err ~3e-8
// vs 3.5e-5 margin); inside the band we evaluate the exact sigmoid.
#define XHI     (-1.0984f)
#define XLO     (-1.0988f)

__device__ __forceinline__ float sigmoidf(float x) {
    return 1.0f / (1.0f + expf(-x));
}

// order-preserving float->uint key (x1 < x2 <=> key1 < key2, unsigned)
__device__ __forceinline__ unsigned int mono_key(unsigned int bits) {
    return (bits & 0x80000000u) ? ~bits : (bits | 0x80000000u);
}
__device__ __forceinline__ unsigned int mono_inv(unsigned int key) {
    return (key & 0x80000000u) ? (key ^ 0x80000000u) : ~key;
}

__device__ __forceinline__ bool conf_pass(float x) {
    if (x >= XHI) return true;
    if (x <= XLO) return false;
    return sigmoidf(x) > CONF;   // rare exact band (~1 element per task)
}

struct PhaseB {
    unsigned long long skey[TOPK];                               // 2400 B
    float bx1[TOPK], by1[TOPK], bx2[TOPK], by2[TOPK], bvv[TOPK]; // 6000 B
    unsigned long long supmask[TOPK][5];                         // 12000 B
};

union U1 {
    unsigned int keys[NA];     // 33600 B (live P1..P4)
    PhaseB pb;                 // 20400 B (live P5..P9)
};

union U2 {
    struct {
        unsigned int hist[NBINS];   // 16384 B (live P1..P2)
        unsigned int wtot[NW];
    } ph;
    unsigned long long cand[CAND_CAP]; // 8192 B (live P4..P5)
};

__global__ __launch_bounds__(NT) void yolo_post(const float* __restrict__ in,
                                                float* __restrict__ out) {
    __shared__ U1 u1;
    __shared__ U2 u2;
    __shared__ unsigned long long keepw[5];
    __shared__ unsigned int s_cnt;
    __shared__ int s_T1;

    const int tid = threadIdx.x;
    const int b = blockIdx.x / NC;
    const int c = blockIdx.x % NC;
    const float* cls = in + (size_t)b * NCH * NA + (size_t)(4 + c) * NA;
    const float* box = in + (size_t)b * NCH * NA;

    // ---- P0: init ----
    for (int i = tid; i < NBINS; i += NT) u2.ph.hist[i] = 0;
    if (tid == 0) { s_cnt = 0; s_T1 = -1; }
    __syncthreads();

    // ---- P1: single pass: monotone logit keys -> LDS, 4096-bin histogram ----
    {
        const float4* cls4 = (const float4*)cls;
        uint4* keys4 = (uint4*)u1.keys;
        for (int q = tid; q < NA / 4; q += NT) {
            float4 x = cls4[q];
            uint4 k;
            k.x = conf_pass(x.x) ? mono_key(__float_as_uint(x.x)) : 0u;
            k.y = conf_pass(x.y) ? mono_key(__float_as_uint(x.y)) : 0u;
            k.z = conf_pass(x.z) ? mono_key(__float_as_uint(x.z)) : 0u;
            k.w = conf_pass(x.w) ? mono_key(__float_as_uint(x.w)) : 0u;
            keys4[q] = k;
            if (k.x) atomicAdd(&u2.ph.hist[k.x >> 20], 1u);
            if (k.y) atomicAdd(&u2.ph.hist[k.y >> 20], 1u);
            if (k.z) atomicAdd(&u2.ph.hist[k.z >> 20], 1u);
            if (k.w) atomicAdd(&u2.ph.hist[k.w >> 20], 1u);
        }
    }
    __syncthreads();

    // ---- P2: crossing bin T1: count(bins > T1) < TARGET <= count(bins >= T1) ----
    {
        const int base = tid * (NBINS / NT);   // 8 bins per thread
        unsigned int v = 0;
#pragma unroll
        for (int k = 0; k < NBINS / NT; ++k) v += u2.ph.hist[base + k];
        const int lane = tid & 63;
        unsigned int s = v;   // inclusive suffix sum within wave
#pragma unroll
        for (int d = 1; d < 64; d <<= 1) {
            unsigned int o = __shfl_down(s, d, 64);
            if (lane + d < 64) s += o;
        }
        if (lane == 0) u2.ph.wtot[tid >> 6] = s;
        __syncthreads();
        unsigned int above_waves = 0;
        for (int wv = (tid >> 6) + 1; wv < NW; ++wv) above_waves += u2.ph.wtot[wv];
        unsigned int acc = (s - v) + above_waves;  // count strictly after this chunk
        for (int bin = base + (NBINS / NT) - 1; bin >= base; --bin) {
            unsigned int cnt = u2.ph.hist[bin];
            if (acc < (unsigned int)TARGET && acc + cnt >= (unsigned int)TARGET) s_T1 = bin;
            acc += cnt;
        }
    }
    __syncthreads();

    // ---- P4: collect all candidates with bin >= T1 (whole crossing bin included) ----
    {
        const unsigned int thrBin = (s_T1 < 0) ? 0u : (unsigned int)s_T1;
        const uint4* keys4 = (const uint4*)u1.keys;
        for (int q = tid; q < NA / 4; q += NT) {
            uint4 k = keys4[q];
            const unsigned int i0 = (unsigned int)q * 4u;
#pragma unroll
            for (int t = 0; t < 4; ++t) {
                unsigned int d = (t == 0) ? k.x : (t == 1) ? k.y : (t == 2) ? k.z : k.w;
                if (d && (d >> 20) >= thrBin) {
                    unsigned int p = atomicAdd(&s_cnt, 1u);
                    if (p < CAND_CAP)
                        u2.cand[p] = ((unsigned long long)d << 32) |
                                     (unsigned long long)(~(i0 + t));
                }
            }
        }
    }
    __syncthreads();
    const int M = min((int)s_cnt, CAND_CAP);
    const int numSel = min(M, TOPK);

    // ---- P5a: exact sigmoid for the M candidates; rekey (s_bits desc, idx asc) ----
    for (int e = tid; e < M; e += NT) {
        unsigned long long k = u2.cand[e];
        unsigned int xkey = (unsigned int)(k >> 32);
        float x = __uint_as_float(mono_inv(xkey));
        float sv = sigmoidf(x);
        u2.cand[e] = ((unsigned long long)__float_as_uint(sv) << 32) |
                     (k & 0xFFFFFFFFull);   // keep ~idx in low word
    }
    __syncthreads();

    // ---- P5b: rank-by-counting (keys unique via ~idx), keep top-300 exactly ----
    for (int e = tid; e < M; e += NT) {
        unsigned long long k = u2.cand[e];
        int rank = 0;
        for (int o = 0; o < M; ++o) rank += (u2.cand[o] > k) ? 1 : 0;
        if (rank < TOPK) u1.pb.skey[rank] = k;   // aliases keys[] — dead after P4
    }
    __syncthreads();

    // ---- P6: gather boxes (cxcywh -> xyxy) + zero supmask ----
    for (int r = tid; r < numSel; r += NT) {
        unsigned long long k = u1.pb.skey[r];
        unsigned int i = ~(unsigned int)(k & 0xFFFFFFFFull);
        float val = __uint_as_float((unsigned int)(k >> 32));
        float cx = box[i];
        float cy = box[NA + i];
        float w  = box[2 * NA + i];
        float h  = box[3 * NA + i];
        float hw = w * 0.5f, hh = h * 0.5f;
        u1.pb.bx1[r] = cx - hw; u1.pb.by1[r] = cy - hh;
        u1.pb.bx2[r] = cx + hw; u1.pb.by2[r] = cy + hh;
        u1.pb.bvv[r] = val;
    }
    for (int t = tid; t < TOPK * 5; t += NT)
        ((unsigned long long*)u1.pb.supmask)[t] = 0ull;
    __syncthreads();

    // ---- P7: suppression bitmask matrix, wave-parallel, diagonal-skipped ----
    {
        const int wave = tid >> 6;
        const int lane = tid & 63;
        for (int i = wave; i < numSel; i += NW) {
            const float x1i = u1.pb.bx1[i], y1i = u1.pb.by1[i];
            const float x2i = u1.pb.bx2[i], y2i = u1.pb.by2[i];
            const float ai = fmaxf(x2i - x1i, 0.0f) * fmaxf(y2i - y1i, 0.0f);
            for (int w = i >> 6; w < 5; ++w) {
                const int j = (w << 6) + lane;
                bool sup = false;
                if (j < numSel && j > i) {
                    float xx1 = fmaxf(x1i, u1.pb.bx1[j]);
                    float yy1 = fmaxf(y1i, u1.pb.by1[j]);
                    float xx2 = fminf(x2i, u1.pb.bx2[j]);
                    float yy2 = fminf(y2i, u1.pb.by2[j]);
                    float iw = fmaxf(xx2 - xx1, 0.0f);
                    float ih = fmaxf(yy2 - yy1, 0.0f);
                    float inter = iw * ih;
                    float aj = fmaxf(u1.pb.bx2[j] - u1.pb.bx1[j], 0.0f) *
                               fmaxf(u1.pb.by2[j] - u1.pb.by1[j], 0.0f);
                    float un = ai + aj - inter;
                    float iou = inter / fmaxf(un, 1e-9f);
                    sup = iou > IOU_T;
                }
                unsigned long long bal = __ballot(sup);
                if (lane == 0) u1.pb.supmask[i][w] = bal;
            }
        }
    }
    __syncthreads();

    // ---- P8: serial greedy suppression scan (thread 0, branchless body) ----
    if (tid == 0) {
        unsigned long long rem0 = 0, rem1 = 0, rem2 = 0, rem3 = 0, rem4 = 0;
        for (int i = 0; i < numSel; ++i) {
            unsigned long long r;
            switch (i >> 6) {
                case 0: r = rem0; break;
                case 1: r = rem1; break;
                case 2: r = rem2; break;
                case 3: r = rem3; break;
                default: r = rem4; break;
            }
            unsigned long long m = ((r >> (i & 63)) & 1ull) - 1ull; // ~0 if keep, 0 if suppressed
            rem0 |= u1.pb.supmask[i][0] & m;
            rem1 |= u1.pb.supmask[i][1] & m;
            rem2 |= u1.pb.supmask[i][2] & m;
            rem3 |= u1.pb.supmask[i][3] & m;
            rem4 |= u1.pb.supmask[i][4] & m;
        }
        keepw[0] = ~rem0; keepw[1] = ~rem1; keepw[2] = ~rem2;
        keepw[3] = ~rem3; keepw[4] = ~rem4;
    }
    __syncthreads();

    // ---- P9: write output rows ----
    float* outp = out + (size_t)blockIdx.x * (TOPK * 6);
    for (int el = tid; el < TOPK * 6; el += NT) {
        const int r = el / 6;
        const int f = el - r * 6;
        float v = 0.0f;
        if (r < numSel && ((keepw[r >> 6] >> (r & 63)) & 1ull)) {
            switch (f) {
                case 0: v = u1.pb.bx1[r]; break;
                case 1: v = u1.pb.by1[r]; break;
                case 2: v = u1.pb.bx2[r]; break;
                case 3: v = u1.pb.by2[r]; break;
                case 4: v = u1.pb.bvv[r]; break;
                default: v = (float)c; break;
            }
        }
        outp[el] = v;
    }
}

extern "C" void kernel_launch(void* const* d_in, const int* in_sizes, int n_in,
                              void* d_out, int out_size, void* d_ws, size_t ws_size,
                              hipStream_t stream) {
    const float* in = (const float*)d_in[0];
    float* out = (float*)d_out;
    yolo_post<<<NB * NC, NT, 0, stream>>>(in, out);
}

// Round 4
// 185.935 us; speedup vs baseline: 1.3823x; 1.0224x over previous
//
#include <hip/hip_runtime.h>
#include <cstdint>

#pragma clang fp contract(off)

#define NB      32
#define NC      18
#define NA      8400
#define NCH     (4 + NC)
#define TOPK    300
#define TARGET  316        // TOPK + margin: absorbs sigmoid-tie rank ambiguity
#define NBINS   4096
#define CAND_CAP 1024
#define CONF    0.25f
#define IOU_T   0.45f
#define NT      512
#define NW      (NT / 64)
// sigmoid(x) > 0.25  <=>  x > -ln(3) = -1.0986123.
// Outside [XLO, XHI] the analytic test is provably exact (fp32 sigmoid err ~3e-8
// vs 3.5e-5 margin); inside the band we evaluate the exact sigmoid.
#define XHI     (-1.0984f)
#define XLO     (-1.0988f)

__device__ __forceinline__ float sigmoidf(float x) {
    return 1.0f / (1.0f + expf(-x));
}

// order-preserving float->uint key (x1 < x2 <=> key1 < key2, unsigned)
__device__ __forceinline__ unsigned int mono_key(unsigned int bits) {
    return (bits & 0x80000000u) ? ~bits : (bits | 0x80000000u);
}
__device__ __forceinline__ unsigned int mono_inv(unsigned int key) {
    return (key & 0x80000000u) ? (key ^ 0x80000000u) : ~key;
}

__device__ __forceinline__ bool conf_pass(float x) {
    if (x >= XHI) return true;
    if (x <= XLO) return false;
    return sigmoidf(x) > CONF;   // rare exact band (~1 element per task)
}

__device__ __forceinline__ unsigned int make_key(float x) {
    return conf_pass(x) ? mono_key(__float_as_uint(x)) : 0u;
}

struct PhaseB {
    unsigned long long skey[TOPK];                               // 2400 B
    float bx1[TOPK], by1[TOPK], bx2[TOPK], by2[TOPK], bvv[TOPK]; // 6000 B
    unsigned long long supmask[TOPK][5];                         // 12000 B
};

// hist is dead after P2; PhaseB is first written in P5b. cand[] must stay
// separate (read in P5b while skey is written).
union U1 {
    unsigned int hist[NBINS];  // 16384 B (live P0..P2)
    PhaseB pb;                 // 20400 B (live P5b..P9)
};

__global__ __launch_bounds__(NT) void yolo_post(const float* __restrict__ in,
                                                float* __restrict__ out) {
    __shared__ U1 u1;
    __shared__ unsigned long long cand[CAND_CAP];  // 8192 B (live P4..P5b)
    __shared__ unsigned int wtot[NW];
    __shared__ unsigned long long keepw[5];
    __shared__ unsigned int s_cnt;
    __shared__ int s_T1;

    const int tid = threadIdx.x;
    const int b = blockIdx.x / NC;
    const int c = blockIdx.x % NC;
    const float* cls = in + (size_t)b * NCH * NA + (size_t)(4 + c) * NA;
    const float* box = in + (size_t)b * NCH * NA;

    // ---- P0: init ----
    for (int i = tid; i < NBINS; i += NT) u1.hist[i] = 0;
    if (tid == 0) { s_cnt = 0; s_T1 = -1; }
    __syncthreads();

    // ---- P1: pass 1: monotone logit keys (registers only) -> 4096-bin histogram ----
    {
        const float4* cls4 = (const float4*)cls;
        for (int q = tid; q < NA / 4; q += NT) {
            float4 x = cls4[q];
            unsigned int kx = make_key(x.x);
            unsigned int ky = make_key(x.y);
            unsigned int kz = make_key(x.z);
            unsigned int kw = make_key(x.w);
            if (kx) atomicAdd(&u1.hist[kx >> 20], 1u);
            if (ky) atomicAdd(&u1.hist[ky >> 20], 1u);
            if (kz) atomicAdd(&u1.hist[kz >> 20], 1u);
            if (kw) atomicAdd(&u1.hist[kw >> 20], 1u);
        }
    }
    __syncthreads();

    // ---- P2: crossing bin T1: count(bins > T1) < TARGET <= count(bins >= T1) ----
    {
        const int base = tid * (NBINS / NT);   // 8 bins per thread
        unsigned int v = 0;
#pragma unroll
        for (int k = 0; k < NBINS / NT; ++k) v += u1.hist[base + k];
        const int lane = tid & 63;
        unsigned int s = v;   // inclusive suffix sum within wave
#pragma unroll
        for (int d = 1; d < 64; d <<= 1) {
            unsigned int o = __shfl_down(s, d, 64);
            if (lane + d < 64) s += o;
        }
        if (lane == 0) wtot[tid >> 6] = s;
        __syncthreads();
        unsigned int above_waves = 0;
        for (int wv = (tid >> 6) + 1; wv < NW; ++wv) above_waves += wtot[wv];
        unsigned int acc = (s - v) + above_waves;  // count strictly after this chunk
        for (int bin = base + (NBINS / NT) - 1; bin >= base; --bin) {
            unsigned int cnt = u1.hist[bin];
            if (acc < (unsigned int)TARGET && acc + cnt >= (unsigned int)TARGET) s_T1 = bin;
            acc += cnt;
        }
    }
    __syncthreads();

    // ---- P4: pass 2 (L2-hot): recompute keys, collect bin >= T1 (crossing bin whole) ----
    {
        const unsigned int thrBin = (s_T1 < 0) ? 0u : (unsigned int)s_T1;
        const float4* cls4 = (const float4*)cls;
        for (int q = tid; q < NA / 4; q += NT) {
            float4 x = cls4[q];
            const unsigned int i0 = (unsigned int)q * 4u;
            unsigned int kk[4];
            kk[0] = make_key(x.x);
            kk[1] = make_key(x.y);
            kk[2] = make_key(x.z);
            kk[3] = make_key(x.w);
#pragma unroll
            for (int t = 0; t < 4; ++t) {
                unsigned int d = kk[t];
                if (d && (d >> 20) >= thrBin) {
                    unsigned int p = atomicAdd(&s_cnt, 1u);
                    if (p < CAND_CAP)
                        cand[p] = ((unsigned long long)d << 32) |
                                  (unsigned long long)(~(i0 + t));
                }
            }
        }
    }
    __syncthreads();
    const int M = min((int)s_cnt, CAND_CAP);
    const int numSel = min(M, TOPK);

    // ---- P5a: exact sigmoid for the M candidates; rekey (s_bits desc, idx asc) ----
    for (int e = tid; e < M; e += NT) {
        unsigned long long k = cand[e];
        unsigned int xkey = (unsigned int)(k >> 32);
        float x = __uint_as_float(mono_inv(xkey));
        float sv = sigmoidf(x);
        cand[e] = ((unsigned long long)__float_as_uint(sv) << 32) |
                  (k & 0xFFFFFFFFull);   // keep ~idx in low word
    }
    __syncthreads();

    // ---- P5b: rank-by-counting (keys unique via ~idx), keep top-300 exactly ----
    for (int e = tid; e < M; e += NT) {
        unsigned long long k = cand[e];
        int rank = 0;
        for (int o = 0; o < M; ++o) rank += (cand[o] > k) ? 1 : 0;
        if (rank < TOPK) u1.pb.skey[rank] = k;   // hist dead — safe alias
    }
    __syncthreads();

    // ---- P6: gather boxes (cxcywh -> xyxy) + zero supmask ----
    for (int r = tid; r < numSel; r += NT) {
        unsigned long long k = u1.pb.skey[r];
        unsigned int i = ~(unsigned int)(k & 0xFFFFFFFFull);
        float val = __uint_as_float((unsigned int)(k >> 32));
        float cx = box[i];
        float cy = box[NA + i];
        float w  = box[2 * NA + i];
        float h  = box[3 * NA + i];
        float hw = w * 0.5f, hh = h * 0.5f;
        u1.pb.bx1[r] = cx - hw; u1.pb.by1[r] = cy - hh;
        u1.pb.bx2[r] = cx + hw; u1.pb.by2[r] = cy + hh;
        u1.pb.bvv[r] = val;
    }
    for (int t = tid; t < TOPK * 5; t += NT)
        ((unsigned long long*)u1.pb.supmask)[t] = 0ull;
    __syncthreads();

    // ---- P7: suppression bitmask matrix, wave-parallel, diagonal-skipped ----
    {
        const int wave = tid >> 6;
        const int lane = tid & 63;
        for (int i = wave; i < numSel; i += NW) {
            const float x1i = u1.pb.bx1[i], y1i = u1.pb.by1[i];
            const float x2i = u1.pb.bx2[i], y2i = u1.pb.by2[i];
            const float ai = fmaxf(x2i - x1i, 0.0f) * fmaxf(y2i - y1i, 0.0f);
            for (int w = i >> 6; w < 5; ++w) {
                const int j = (w << 6) + lane;
                bool sup = false;
                if (j < numSel && j > i) {
                    float xx1 = fmaxf(x1i, u1.pb.bx1[j]);
                    float yy1 = fmaxf(y1i, u1.pb.by1[j]);
                    float xx2 = fminf(x2i, u1.pb.bx2[j]);
                    float yy2 = fminf(y2i, u1.pb.by2[j]);
                    float iw = fmaxf(xx2 - xx1, 0.0f);
                    float ih = fmaxf(yy2 - yy1, 0.0f);
                    float inter = iw * ih;
                    float aj = fmaxf(u1.pb.bx2[j] - u1.pb.bx1[j], 0.0f) *
                               fmaxf(u1.pb.by2[j] - u1.pb.by1[j], 0.0f);
                    float un = ai + aj - inter;
                    float iou = inter / fmaxf(un, 1e-9f);
                    sup = iou > IOU_T;
                }
                unsigned long long bal = __ballot(sup);
                if (lane == 0) u1.pb.supmask[i][w] = bal;
            }
        }
    }
    __syncthreads();

    // ---- P8: serial greedy suppression scan (thread 0, branchless body) ----
    if (tid == 0) {
        unsigned long long rem0 = 0, rem1 = 0, rem2 = 0, rem3 = 0, rem4 = 0;
        for (int i = 0; i < numSel; ++i) {
            unsigned long long r;
            switch (i >> 6) {
                case 0: r = rem0; break;
                case 1: r = rem1; break;
                case 2: r = rem2; break;
                case 3: r = rem3; break;
                default: r = rem4; break;
            }
            unsigned long long m = ((r >> (i & 63)) & 1ull) - 1ull; // ~0 keep, 0 suppressed
            rem0 |= u1.pb.supmask[i][0] & m;
            rem1 |= u1.pb.supmask[i][1] & m;
            rem2 |= u1.pb.supmask[i][2] & m;
            rem3 |= u1.pb.supmask[i][3] & m;
            rem4 |= u1.pb.supmask[i][4] & m;
        }
        keepw[0] = ~rem0; keepw[1] = ~rem1; keepw[2] = ~rem2;
        keepw[3] = ~rem3; keepw[4] = ~rem4;
    }
    __syncthreads();

    // ---- P9: write output rows ----
    float* outp = out + (size_t)blockIdx.x * (TOPK * 6);
    for (int el = tid; el < TOPK * 6; el += NT) {
        const int r = el / 6;
        const int f = el - r * 6;
        float v = 0.0f;
        if (r < numSel && ((keepw[r >> 6] >> (r & 63)) & 1ull)) {
            switch (f) {
                case 0: v = u1.pb.bx1[r]; break;
                case 1: v = u1.pb.by1[r]; break;
                case 2: v = u1.pb.bx2[r]; break;
                case 3: v = u1.pb.by2[r]; break;
                case 4: v = u1.pb.bvv[r]; break;
                default: v = (float)c; break;
            }
        }
        outp[el] = v;
    }
}

extern "C" void kernel_launch(void* const* d_in, const int* in_sizes, int n_in,
                              void* d_out, int out_size, void* d_ws, size_t ws_size,
                              hipStream_t stream) {
    const float* in = (const float*)d_in[0];
    float* out = (float*)d_out;
    yolo_post<<<NB * NC, NT, 0, stream>>>(in, out);
}